// Round 1
// baseline (1539.399 us; speedup 1.0000x reference)
//
#include <hip/hip_runtime.h>
#include <hip/hip_bf16.h>
#include <math.h>

#define B_  32
#define L_  512
#define C_  862
#define P_  720
#define H2_ 1024
#define M_  (B_*C_)   // 27584 rows

// ---------------------------------------------------------------- DCT matrix
__global__ __launch_bounds__(256) void build_dct(float* __restrict__ D) {
    int idx = blockIdx.x * 256 + threadIdx.x;
    if (idx >= L_ * L_) return;
    int k = idx >> 9, l = idx & 511;
    double ang = M_PI * (double)((2 * l + 1) * k) / (2.0 * (double)L_);
    D[idx] = (float)(2.0 * cos(ang));
}

// ---------------------------------------------------- x (B,L,C) -> Xc (B*C,L)
__global__ __launch_bounds__(256) void transpose_x(const float* __restrict__ x,
                                                   float* __restrict__ Xc) {
    __shared__ float tile[32][33];
    int b  = blockIdx.z;
    int c0 = blockIdx.x * 32;
    int l0 = blockIdx.y * 32;
    int tx = threadIdx.x & 31, ty = threadIdx.x >> 5;   // 32 x 8
#pragma unroll
    for (int i = 0; i < 4; ++i) {
        int l = l0 + ty + i * 8, c = c0 + tx;
        float v = 0.f;
        if (l < L_ && c < C_) v = x[((size_t)b * L_ + l) * C_ + c];
        tile[ty + i * 8][tx] = v;           // tile[l_local][c_local]
    }
    __syncthreads();
#pragma unroll
    for (int i = 0; i < 4; ++i) {
        int c = c0 + ty + i * 8, l = l0 + tx;
        if (c < C_ && l < L_)
            Xc[((size_t)b * C_ + c) * L_ + l] = tile[tx][ty + i * 8];
    }
}

// -------------------------------------------------------- row LayerNorm (512)
__global__ __launch_bounds__(256) void layernorm_rows(float* __restrict__ X,
                                                      const float* __restrict__ gamma,
                                                      const float* __restrict__ beta) {
    int row = blockIdx.x;
    float* p = X + (size_t)row * L_;
    int tid = threadIdx.x;
    float v0 = p[tid], v1 = p[tid + 256];
    float s = v0 + v1, q = v0 * v0 + v1 * v1;
#pragma unroll
    for (int off = 32; off; off >>= 1) {
        s += __shfl_down(s, off);
        q += __shfl_down(q, off);
    }
    __shared__ float ss[4], sq[4];
    int wid = tid >> 6, lane = tid & 63;
    if (lane == 0) { ss[wid] = s; sq[wid] = q; }
    __syncthreads();
    if (tid == 0) {
        float S = ss[0] + ss[1] + ss[2] + ss[3];
        float Q = sq[0] + sq[1] + sq[2] + sq[3];
        float mu  = S * (1.f / L_);
        float var = Q * (1.f / L_) - mu * mu;
        ss[0] = mu;
        sq[0] = rsqrtf(var + 1e-6f);
    }
    __syncthreads();
    float mu = ss[0], r = sq[0];
    p[tid]       = (v0 - mu) * r * gamma[tid]       + beta[tid];
    p[tid + 256] = (v1 - mu) * r * gamma[tid + 256] + beta[tid + 256];
}

// ------------------------------------------------------------- fp32 NT GEMM
// C[M,N] = act( (A .* A2?) [M,K] * W[N,K]^T + bias? )
// ACT: 0 none, 1 relu, 2 sigmoid. SCATTER: store to (B,P,C) layout.
template <int ACT, bool MULA2, bool BIAS, bool SCATTER>
__global__ __launch_bounds__(256)
void gemm_nt(const float* __restrict__ A, const float* __restrict__ A2,
             const float* __restrict__ W, const float* __restrict__ bias,
             float* __restrict__ Cout, int M, int N, int K) {
    constexpr int BM = 128, BN = 64, BK = 16;
    __shared__ float As[BK][BM];
    __shared__ float Ws[BK][BN];
    int tid = threadIdx.x;
    int bm = blockIdx.y * BM;
    int bn = blockIdx.x * BN;
    int tx = tid & 15;     // N dir: 16 cols of 4
    int ty = tid >> 4;     // M dir: 16 rows of 8
    int kq = tid & 3;      // float4 along K
    int lr = tid >> 2;     // 0..63

    float acc[8][4] = {};

    for (int k0 = 0; k0 < K; k0 += BK) {
#pragma unroll
        for (int h = 0; h < 2; ++h) {
            int m = bm + lr + h * 64;
            float4 v = make_float4(0.f, 0.f, 0.f, 0.f);
            if (m < M) {
                v = *reinterpret_cast<const float4*>(A + (size_t)m * K + k0 + kq * 4);
                if (MULA2) {
                    float4 w = *reinterpret_cast<const float4*>(A2 + (size_t)m * K + k0 + kq * 4);
                    v.x *= w.x; v.y *= w.y; v.z *= w.z; v.w *= w.w;
                }
            }
            As[kq * 4 + 0][lr + h * 64] = v.x;
            As[kq * 4 + 1][lr + h * 64] = v.y;
            As[kq * 4 + 2][lr + h * 64] = v.z;
            As[kq * 4 + 3][lr + h * 64] = v.w;
        }
        {
            int n = bn + lr;
            float4 v = make_float4(0.f, 0.f, 0.f, 0.f);
            if (n < N)
                v = *reinterpret_cast<const float4*>(W + (size_t)n * K + k0 + kq * 4);
            Ws[kq * 4 + 0][lr] = v.x;
            Ws[kq * 4 + 1][lr] = v.y;
            Ws[kq * 4 + 2][lr] = v.z;
            Ws[kq * 4 + 3][lr] = v.w;
        }
        __syncthreads();
#pragma unroll
        for (int kk = 0; kk < BK; ++kk) {
            float4 a0 = *reinterpret_cast<const float4*>(&As[kk][ty * 8]);
            float4 a1 = *reinterpret_cast<const float4*>(&As[kk][ty * 8 + 4]);
            float4 bv = *reinterpret_cast<const float4*>(&Ws[kk][tx * 4]);
            float a[8] = {a0.x, a0.y, a0.z, a0.w, a1.x, a1.y, a1.z, a1.w};
            float b[4] = {bv.x, bv.y, bv.z, bv.w};
#pragma unroll
            for (int i = 0; i < 8; ++i)
#pragma unroll
                for (int j = 0; j < 4; ++j) acc[i][j] = fmaf(a[i], b[j], acc[i][j]);
        }
        __syncthreads();
    }

#pragma unroll
    for (int i = 0; i < 8; ++i) {
        int m = bm + ty * 8 + i;
        if (m >= M) continue;
#pragma unroll
        for (int j = 0; j < 4; ++j) {
            int n = bn + tx * 4 + j;
            if (n >= N) continue;
            float v = acc[i][j];
            if (BIAS) v += bias[n];
            if (ACT == 1) v = fmaxf(v, 0.f);
            if (ACT == 2) v = 1.f / (1.f + __expf(-v));
            if (SCATTER) {
                int b = m / C_;
                int c = m - b * C_;
                Cout[(size_t)b * (P_ * C_) + (size_t)n * C_ + c] = v;
            } else {
                Cout[(size_t)m * N + n] = v;
            }
        }
    }
}

extern "C" void kernel_launch(void* const* d_in, const int* in_sizes, int n_in,
                              void* d_out, int out_size, void* d_ws, size_t ws_size,
                              hipStream_t stream) {
    const float* x     = (const float*)d_in[0];
    const float* W1    = (const float*)d_in[1];
    const float* W2    = (const float*)d_in[2];
    const float* gamma = (const float*)d_in[3];
    const float* beta  = (const float*)d_in[4];
    const float* Wl    = (const float*)d_in[5];
    const float* bl    = (const float*)d_in[6];
    float* out = (float*)d_out;

    float* ws = (float*)d_ws;
    float* Xc = ws;                              // M_*512
    float* F  = Xc + (size_t)M_ * L_;            // M_*512 (freq, then f_weight)
    float* Hb = F  + (size_t)M_ * L_;            // M_*1024
    float* Dm = Hb + (size_t)M_ * H2_;           // 512*512

    build_dct<<<(L_ * L_ + 255) / 256, 256, 0, stream>>>(Dm);
    transpose_x<<<dim3((C_ + 31) / 32, (L_ + 31) / 32, B_), 256, 0, stream>>>(x, Xc);

    // Stage A: freq = Xc * D^T   (M x 512, K=512)
    gemm_nt<0, false, false, false><<<dim3(L_ / 64, (M_ + 127) / 128), 256, 0, stream>>>(
        Xc, nullptr, Dm, nullptr, F, M_, L_, L_);
    layernorm_rows<<<M_, 256, 0, stream>>>(F, gamma, beta);

    // Stage B: h = relu(Fn * W1^T)   (M x 1024, K=512)
    gemm_nt<1, false, false, false><<<dim3(H2_ / 64, (M_ + 127) / 128), 256, 0, stream>>>(
        F, nullptr, W1, nullptr, Hb, M_, H2_, L_);

    // Stage C: fw = sigmoid(H * W2^T)   (M x 512, K=1024)
    gemm_nt<2, false, false, false><<<dim3(L_ / 64, (M_ + 127) / 128), 256, 0, stream>>>(
        Hb, nullptr, W2, nullptr, F, M_, L_, H2_);
    layernorm_rows<<<M_, 256, 0, stream>>>(F, gamma, beta);

    // Stage D: out = (Xc .* Fwn) * Wl^T + bl, scattered to (B,P,C)
    gemm_nt<0, true, true, true><<<dim3((P_ + 63) / 64, (M_ + 127) / 128), 256, 0, stream>>>(
        Xc, F, Wl, bl, out, M_, P_, L_);
}

// Round 2
// 285.135 us; speedup vs baseline: 5.3988x; 5.3988x over previous
//
#include <hip/hip_runtime.h>
#include <hip/hip_bf16.h>
#include <math.h>

#define B_   32
#define L_   512
#define C_   862
#define P_   720
#define H2_  1024
#define M_   (B_*C_)     // 27584 real rows
#define MP_  27648       // padded to multiple of 128
#define PP_  768         // P padded to multiple of 128

typedef __hip_bfloat16 bf16;
typedef __attribute__((ext_vector_type(8))) short s16x8;
typedef __attribute__((ext_vector_type(4))) float f32x4;

__device__ __forceinline__ void gload_lds16(const bf16* g, bf16* lds) {
    __builtin_amdgcn_global_load_lds(
        (const __attribute__((address_space(1))) void*)g,
        (__attribute__((address_space(3))) void*)lds, 16, 0, 0);
}

// ---------------------------------------------------------------- DCT matrix (bf16)
__global__ __launch_bounds__(256) void build_dct(bf16* __restrict__ D) {
    int idx = blockIdx.x * 256 + threadIdx.x;
    if (idx >= L_ * L_) return;
    int k = idx >> 9, l = idx & 511;
    double ang = M_PI * (double)((2 * l + 1) * k) / (2.0 * (double)L_);
    D[idx] = __float2bfloat16((float)(2.0 * cos(ang)));
}

// ------------------------------------------------------------- fp32 -> bf16 convert
__global__ __launch_bounds__(256) void cvt_bf16(const float* __restrict__ in,
                                                bf16* __restrict__ out, int n) {
    int i = blockIdx.x * 256 + threadIdx.x;
    if (i < n) out[i] = __float2bfloat16(in[i]);
}

// Wl (720,512) -> bf16 padded to (768,512) with zeros
__global__ __launch_bounds__(256) void cvt_wl_pad(const float* __restrict__ in,
                                                  bf16* __restrict__ out) {
    int i = blockIdx.x * 256 + threadIdx.x;
    if (i >= PP_ * L_) return;
    int r = i >> 9;
    out[i] = (r < P_) ? __float2bfloat16(in[i]) : __float2bfloat16(0.f);
}

// ---------------------------------------------------- x (B,L,C) -> Xc (B*C,L) bf16
__global__ __launch_bounds__(256) void transpose_x(const float* __restrict__ x,
                                                   bf16* __restrict__ Xc) {
    __shared__ float tile[32][33];
    int b  = blockIdx.z;
    int c0 = blockIdx.x * 32;
    int l0 = blockIdx.y * 32;
    int tx = threadIdx.x & 31, ty = threadIdx.x >> 5;   // 32 x 8
#pragma unroll
    for (int i = 0; i < 4; ++i) {
        int l = l0 + ty + i * 8, c = c0 + tx;
        float v = 0.f;
        if (l < L_ && c < C_) v = x[((size_t)b * L_ + l) * C_ + c];
        tile[ty + i * 8][tx] = v;
    }
    __syncthreads();
#pragma unroll
    for (int i = 0; i < 4; ++i) {
        int c = c0 + ty + i * 8, l = l0 + tx;
        if (c < C_ && l < L_)
            Xc[((size_t)b * C_ + c) * L_ + l] = __float2bfloat16(tile[tx][ty + i * 8]);
    }
}

// ------------------- row LayerNorm (512) fp32 in -> bf16 out; MUL: multiply by Xc
template <bool MUL>
__global__ __launch_bounds__(256) void layernorm_rows(const float* __restrict__ X,
                                                      const bf16* __restrict__ Xc,
                                                      const float* __restrict__ gamma,
                                                      const float* __restrict__ beta,
                                                      bf16* __restrict__ Out) {
    int row = blockIdx.x;
    const float* p = X + (size_t)row * L_;
    int tid = threadIdx.x;
    float v0 = p[tid], v1 = p[tid + 256];
    float s = v0 + v1, q = v0 * v0 + v1 * v1;
#pragma unroll
    for (int off = 32; off; off >>= 1) {
        s += __shfl_down(s, off);
        q += __shfl_down(q, off);
    }
    __shared__ float ss[4], sq[4];
    int wid = tid >> 6, lane = tid & 63;
    if (lane == 0) { ss[wid] = s; sq[wid] = q; }
    __syncthreads();
    if (tid == 0) {
        float S = ss[0] + ss[1] + ss[2] + ss[3];
        float Q = sq[0] + sq[1] + sq[2] + sq[3];
        float mu  = S * (1.f / L_);
        float var = Q * (1.f / L_) - mu * mu;
        ss[0] = mu;
        sq[0] = rsqrtf(var + 1e-6f);
    }
    __syncthreads();
    float mu = ss[0], r = sq[0];
    float y0 = (v0 - mu) * r * gamma[tid]       + beta[tid];
    float y1 = (v1 - mu) * r * gamma[tid + 256] + beta[tid + 256];
    if (MUL) {
        y0 *= __bfloat162float(Xc[(size_t)row * L_ + tid]);
        y1 *= __bfloat162float(Xc[(size_t)row * L_ + tid + 256]);
    }
    Out[(size_t)row * L_ + tid]       = __float2bfloat16(y0);
    Out[(size_t)row * L_ + tid + 256] = __float2bfloat16(y1);
}

// ------------------------------------------------------------- bf16 MFMA NT GEMM
// C[m,n] = act( A[m,:] . B[n,:] ) (+ bias[m] if BIAS_ROW)
// Tile 128x128, BK=32, 4 waves (2x2), each wave 64x64 via 4x4 x mfma_16x16x32.
// M,N are PADDED multiples of 128; stores guarded by Mreal/Nreal.
// SCATTER_BC: n is flattened (b,c); store to out[b][m][c] (out is (B,P,C)).
template <int ACT, bool OUT_BF16, bool BIAS_ROW, bool SCATTER_BC>
__global__ __launch_bounds__(256, 2)
void gemm_bf16(const bf16* __restrict__ A, const bf16* __restrict__ Bm,
               const float* __restrict__ bias, void* __restrict__ Cout,
               int M, int N, int K, int Mreal, int Nreal) {
    constexpr int BK = 32;
    __shared__ bf16 As[128][BK];
    __shared__ bf16 Bs[128][BK];
    int tid  = threadIdx.x;
    int wave = tid >> 6, lane = tid & 63;
    int wr = wave >> 1, wc = wave & 1;            // 2x2 waves of 64x64
    size_t bm = (size_t)blockIdx.y * 128;
    size_t bn = (size_t)blockIdx.x * 128;

    f32x4 acc[4][4] = {};

    const bf16* Ab = A + bm * K;
    const bf16* Bb = Bm + bn * K;
    int srow = lane >> 2;            // 0..15
    int scol = (lane & 3) * 8;       // k elements
    int r0 = wave * 32;

    for (int k0 = 0; k0 < K; k0 += BK) {
        gload_lds16(Ab + (size_t)(r0 + srow)      * K + k0 + scol, &As[r0][0]);
        gload_lds16(Ab + (size_t)(r0 + 16 + srow) * K + k0 + scol, &As[r0 + 16][0]);
        gload_lds16(Bb + (size_t)(r0 + srow)      * K + k0 + scol, &Bs[r0][0]);
        gload_lds16(Bb + (size_t)(r0 + 16 + srow) * K + k0 + scol, &Bs[r0 + 16][0]);
        __syncthreads();

        int fr = lane & 15, kq = (lane >> 4) * 8;
        s16x8 af[4], bfv[4];
#pragma unroll
        for (int f = 0; f < 4; ++f) {
            af[f]  = *reinterpret_cast<const s16x8*>(&As[wr * 64 + f * 16 + fr][kq]);
            bfv[f] = *reinterpret_cast<const s16x8*>(&Bs[wc * 64 + f * 16 + fr][kq]);
        }
#pragma unroll
        for (int i = 0; i < 4; ++i)
#pragma unroll
            for (int j = 0; j < 4; ++j)
                acc[i][j] = __builtin_amdgcn_mfma_f32_16x16x32_bf16(af[i], bfv[j], acc[i][j], 0, 0, 0);
        __syncthreads();
    }

    int fr = lane & 15, fq = lane >> 4;
#pragma unroll
    for (int i = 0; i < 4; ++i) {
#pragma unroll
        for (int j = 0; j < 4; ++j) {
#pragma unroll
            for (int r = 0; r < 4; ++r) {
                int m = (int)bm + wr * 64 + i * 16 + fq * 4 + r;
                int n = (int)bn + wc * 64 + j * 16 + fr;
                if (m < Mreal && n < Nreal) {
                    float v = acc[i][j][r];
                    if (BIAS_ROW) v += bias[m];
                    if (ACT == 1) v = fmaxf(v, 0.f);
                    if (ACT == 2) v = 1.f / (1.f + __expf(-v));
                    if (SCATTER_BC) {
                        int b = n / C_;
                        int c = n - b * C_;
                        ((float*)Cout)[(size_t)b * (P_ * C_) + (size_t)m * C_ + c] = v;
                    } else if (OUT_BF16) {
                        ((bf16*)Cout)[(size_t)m * N + n] = __float2bfloat16(v);
                    } else {
                        ((float*)Cout)[(size_t)m * N + n] = v;
                    }
                }
            }
        }
    }
}

extern "C" void kernel_launch(void* const* d_in, const int* in_sizes, int n_in,
                              void* d_out, int out_size, void* d_ws, size_t ws_size,
                              hipStream_t stream) {
    const float* x     = (const float*)d_in[0];
    const float* W1    = (const float*)d_in[1];
    const float* W2    = (const float*)d_in[2];
    const float* gamma = (const float*)d_in[3];
    const float* beta  = (const float*)d_in[4];
    const float* Wl    = (const float*)d_in[5];
    const float* bl    = (const float*)d_in[6];
    float* out = (float*)d_out;

    char* ws = (char*)d_ws;
    bf16*  Xc   = (bf16*)ws;                                  // MP_*512 bf16
    bf16*  Fn   = Xc + (size_t)MP_ * L_;                      // MP_*512 bf16 (Fn, then Prod)
    bf16*  Hb   = Fn + (size_t)MP_ * L_;                      // MP_*1024 bf16
    float* Ff   = (float*)(Hb + (size_t)MP_ * H2_);           // MP_*512 f32 (freq, then fw)
    bf16*  Dbf  = (bf16*)(Ff + (size_t)MP_ * L_);             // 512*512
    bf16*  W1bf = Dbf + (size_t)L_ * L_;                      // 1024*512
    bf16*  W2bf = W1bf + (size_t)H2_ * L_;                    // 512*1024
    bf16*  Wlbf = W2bf + (size_t)L_ * H2_;                    // 768*512

    build_dct<<<(L_ * L_ + 255) / 256, 256, 0, stream>>>(Dbf);
    cvt_bf16<<<(H2_ * L_ + 255) / 256, 256, 0, stream>>>(W1, W1bf, H2_ * L_);
    cvt_bf16<<<(L_ * H2_ + 255) / 256, 256, 0, stream>>>(W2, W2bf, L_ * H2_);
    cvt_wl_pad<<<(PP_ * L_ + 255) / 256, 256, 0, stream>>>(Wl, Wlbf);
    transpose_x<<<dim3((C_ + 31) / 32, (L_ + 31) / 32, B_), 256, 0, stream>>>(x, Xc);

    // Stage A: freq = Xc . D^T   (f32 out)
    gemm_bf16<0, false, false, false><<<dim3(L_ / 128, MP_ / 128), 256, 0, stream>>>(
        Xc, Dbf, nullptr, Ff, MP_, L_, L_, M_, L_);
    layernorm_rows<false><<<M_, 256, 0, stream>>>(Ff, nullptr, gamma, beta, Fn);

    // Stage B: H = relu(Fn . W1^T)  (bf16 out)
    gemm_bf16<1, true, false, false><<<dim3(H2_ / 128, MP_ / 128), 256, 0, stream>>>(
        Fn, W1bf, nullptr, Hb, MP_, H2_, L_, M_, H2_);

    // Stage C: fw = sigmoid(H . W2^T)  (f32 out)
    gemm_bf16<2, false, false, false><<<dim3(L_ / 128, MP_ / 128), 256, 0, stream>>>(
        Hb, W2bf, nullptr, Ff, MP_, L_, H2_, M_, L_);
    // Prod = LN(fw) * Xc  (bf16, into Fn buffer)
    layernorm_rows<true><<<M_, 256, 0, stream>>>(Ff, Xc, gamma, beta, Fn);

    // Stage D: out[b,p,c] = Wl[p,:] . Prod[(b,c),:] + bl[p]  (operand-swapped, coalesced store)
    gemm_bf16<0, false, true, true><<<dim3(MP_ / 128, PP_ / 128), 256, 0, stream>>>(
        Wlbf, Fn, bl, out, PP_, MP_, L_, P_, M_);
}